// Round 1
// 116.969 us; speedup vs baseline: 1.0033x; 1.0033x over previous
//
#include <hip/hip_runtime.h>
#include <hip/hip_bf16.h>

// Problem dims (fixed by the reference setup_inputs)
#define BB 8
#define TT 4096
#define SS 256
#define DD 512

typedef __attribute__((ext_vector_type(8))) short short8;
typedef __attribute__((ext_vector_type(4))) float floatx4;
typedef __attribute__((ext_vector_type(4))) int intx4;

// Packed RNE f32x2 -> bf16x2 (v_cvt_pk_bf16_f32 on gfx950).
__device__ inline int pk2(float a, float b) {
  __hip_bfloat162 h = __float22bfloat162_rn(make_float2(a, b));
  int r;
  __builtin_memcpy(&r, &h, 4);
  return r;
}

// Pack 8 consecutive-k f32 values into a bf16 MFMA fragment.
__device__ inline short8 cvt8(float4 f0, float4 f1) {
  intx4 p;
  p[0] = pk2(f0.x, f0.y);
  p[1] = pk2(f0.z, f0.w);
  p[2] = pk2(f1.x, f1.y);
  p[3] = pk2(f1.z, f1.w);
  return __builtin_bit_cast(short8, p);
}

// K1 v2: pack spk (8,256,512) f32 -> bf16 in MFMA-FRAGMENT order so the
// fused kernel loads each B fragment as ONE coalesced global_load_dwordx4
// per wave (64 lanes x 16 B = 1 KiB contiguous). No LDS staging for B at
// all in K2 -> frees LDS for double-buffered A and removes B from the
// barrier-drain path.
//   frag_idx = ((((b*2+tn)*2+wn)*8+kt)*2+ks)*4 + in   (512 shorts each)
//   lane l of frag: row = tn*128+wn*64+in*16+(l&15),
//                   k   = kt*64+ks*32+(l>>4)*8 .. +8
__global__ __launch_bounds__(256) void cos_packB_kernel(
    const float* __restrict__ spk, short* __restrict__ bp) {
  const int id = blockIdx.x;  // 512 blocks = (b, tn, wn, kt, ks)
  const int ks = id & 1;
  const int kt = (id >> 1) & 7;
  const int wn = (id >> 4) & 1;
  const int tn = (id >> 5) & 1;
  const int b = id >> 6;
  const int t = threadIdx.x;  // 256 = 4 in x 64 lane
  const int in = t >> 6;
  const int lane = t & 63;
  const int row = tn * 128 + wn * 64 + in * 16 + (lane & 15);
  const int k = kt * 64 + ks * 32 + (lane >> 4) * 8;
  const float* src = spk + ((size_t)(b * SS + row)) * DD + k;
  float4 f0 = *(const float4*)src;
  float4 f1 = *(const float4*)(src + 4);
  short8 o = cvt8(f0, f1);
  size_t frag = (size_t)((((b * 2 + tn) * 2 + wn) * 8 + kt) * 2 + ks) * 4 + in;
  *(short8*)(bp + frag * 512 + (size_t)lane * 8) = o;
}

// K2: fused cosine scorer, 128x128 tile, 4 waves (2x2).
//  - A: f32, BK=64, global_load_lds width=16, XOR-16 swizzle (proven
//    conflict-free), now DOUBLE-BUFFERED (2x32 KB) with ONE barrier per kt:
//    issue stage(kt+1) -> compute(kt) -> syncthreads (drains the DMA that
//    overlapped compute). Previous version exposed the full DMA latency
//    between two barriers every kt.
//  - B: fragment-ordered bf16 loaded straight to registers (coalesced 1 KiB
//    per wave per frag). Issued BEFORE the A-DMA each kt so the compiler's
//    vmcnt wait for B (oldest-first semantics) does not drain the A stage.
//  - XCD-pair swizzle: id%8 = XCD; both tn halves of one (b,tm) A panel run
//    adjacently on the same XCD -> A fetched from HBM once, second read is
//    an L2 hit. Each XCD also owns exactly one b -> bp/spk fully L2-local.
//  - scX/scY alias sA after the k-loop -> LDS stays at exactly 64 KB,
//    2 blocks/CU.
__global__ __launch_bounds__(256) void cos_fused_kernel(
    const float* __restrict__ xs, const short* __restrict__ bp,
    float* __restrict__ out) {
  __shared__ float sA[2 * 128 * 64];  // 64 KB: double-buffered A tile
  float* scX = sA;                    // aliased: only used after the k-loop
  float* scY = sA + 128;

  const int tid = threadIdx.x;
  const int wave = tid >> 6;
  const int lane = tid & 63;

  // XCD-pair swizzle (bijective over 512 blocks).
  const int id = blockIdx.x;
  const int xcd = id & 7;
  const int j = id >> 3;                     // 0..63 (per-XCD slot)
  const int pairIdx = xcd * 32 + (j >> 1);   // 0..255
  const int tn = j & 1;                      // tn pair adjacent on same XCD
  const int tm = pairIdx & 31;
  const int b = pairIdx >> 5;                // XCD x owns batch b == x

  const int wm = wave >> 1;
  const int wn = wave & 1;
  const int quad = lane >> 4;
  const int l15 = lane & 15;
  const bool gramA = (wm == wn);

  const float* Abase = xs + ((size_t)b * TT + tm * 128) * DD;
  // Per-wave, per-lane B fragment base (shorts).
  const short* Bw =
      bp + (size_t)((b * 2 + tn) * 2 + wn) * 32768 + (size_t)lane * 8;

  floatx4 acc[4][4];
#pragma unroll
  for (int i = 0; i < 4; i++)
#pragma unroll
    for (int jj = 0; jj < 4; jj++) acc[i][jj] = (floatx4){0.f, 0.f, 0.f, 0.f};
  floatx4 accG[4];  // gram accumulators (A-rows if wm==wn else B-rows)
#pragma unroll
  for (int i = 0; i < 4; i++) accG[i] = (floatx4){0.f, 0.f, 0.f, 0.f};

  // A staging map: 16B unit s = jj*256 + tid; row = s>>4; slot s&15 holds
  // logical k-block (s&15) ^ (row&15)  [XOR-16 swizzle].
  int aoff[8];
#pragma unroll
  for (int jj = 0; jj < 8; jj++) {
    int s = jj * 256 + tid;
    int row = s >> 4;
    int blk = (s & 15) ^ (row & 15);
    aoff[jj] = row * DD + blk * 4;
  }

  // Prologue: stage kt=0 into buffer 0, full drain once.
#pragma unroll
  for (int jj = 0; jj < 8; jj++) {
    __builtin_amdgcn_global_load_lds(
        (const __attribute__((address_space(1))) unsigned int*)(Abase +
            aoff[jj]),
        (__attribute__((address_space(3))) unsigned int*)(sA +
            (jj * 256 + wave * 64) * 4),
        16, 0, 0);
  }
  __syncthreads();

  for (int kt = 0; kt < 8; ++kt) {
    const int cur = kt & 1;

    // B fragments for this kt -> registers. Issued FIRST so the vmcnt wait
    // on them (oldest-first) completes without draining the A DMA below.
    short8 breg[2][4];
    const short* Bkt = Bw + kt * 4096;
#pragma unroll
    for (int ksl = 0; ksl < 2; ksl++)
#pragma unroll
      for (int in = 0; in < 4; in++)
        breg[ksl][in] = *(const short8*)(Bkt + ksl * 2048 + in * 512);

    // Stage kt+1 into the other buffer; overlaps this kt's compute, drained
    // only at the single syncthreads at the bottom.
    if (kt < 7) {
#pragma unroll
      for (int jj = 0; jj < 8; jj++) {
        __builtin_amdgcn_global_load_lds(
            (const __attribute__((address_space(1))) unsigned int*)(Abase +
                aoff[jj] + (kt + 1) * 64),
            (__attribute__((address_space(3))) unsigned int*)(sA +
                (cur ^ 1) * 8192 + (jj * 256 + wave * 64) * 4),
            16, 0, 0);
      }
    }

    const float* sAc = sA + cur * 8192;
#pragma unroll
    for (int ks = 0; ks < 2; ks++) {
      short8 af[4];
      const int b0s = ks * 8 + quad * 2;  // first 16B f32 block of A frag
#pragma unroll
      for (int im = 0; im < 4; im++) {
        int row = wm * 64 + im * 16 + l15;
        int s0 = b0s ^ (row & 15);
        int s1 = (b0s + 1) ^ (row & 15);
        float4 f0 = *(const float4*)(sAc + row * 64 + s0 * 4);
        float4 f1 = *(const float4*)(sAc + row * 64 + s1 * 4);
        af[im] = cvt8(f0, f1);
      }
#pragma unroll
      for (int im = 0; im < 4; im++)
#pragma unroll
        for (int in = 0; in < 4; in++)
          acc[im][in] = __builtin_amdgcn_mfma_f32_16x16x32_bf16(
              af[im], breg[ks][in], acc[im][in], 0, 0, 0);
      if (gramA) {
#pragma unroll
        for (int im = 0; im < 4; im++)
          accG[im] = __builtin_amdgcn_mfma_f32_16x16x32_bf16(
              af[im], af[im], accG[im], 0, 0, 0);
      } else {
#pragma unroll
        for (int in = 0; in < 4; in++)
          accG[in] = __builtin_amdgcn_mfma_f32_16x16x32_bf16(
              breg[ks][in], breg[ks][in], accG[in], 0, 0, 0);
      }
    }
    __syncthreads();  // single barrier per kt: syncs reads + drains DMA
  }

  // Extract gram diagonals -> inverse norms. C/D layout: col = l15,
  // row = quad*4 + r; diagonal element d: lane l15==d, quad==d>>2, r=d&3.
  // scX/scY alias sA: all sA reads finished before the loop's last barrier.
  if (quad == (l15 >> 2)) {
#pragma unroll
    for (int i = 0; i < 4; i++) {
      float inv = 1.0f / fmaxf(sqrtf(accG[i][l15 & 3]), 1e-8f);
      if (gramA)
        scX[wm * 64 + i * 16 + l15] = inv;  // waves (0,0),(1,1): rows 0..127
      else
        scY[wn * 64 + i * 16 + l15] = inv;  // waves (0,1),(1,0): cols 0..127
    }
  }
  __syncthreads();

  // Epilogue: apply cosine scales (dot * (1/||x||) * (1/||y||)).
  float* Obase = out + ((size_t)b * TT + tm * 128) * SS + tn * 128;
#pragma unroll
  for (int im = 0; im < 4; im++) {
#pragma unroll
    for (int in = 0; in < 4; in++) {
      int col = wn * 64 + in * 16 + l15;
      float yv = scY[col];
#pragma unroll
      for (int r = 0; r < 4; r++) {
        int row = wm * 64 + im * 16 + quad * 4 + r;
        Obase[row * SS + col] = acc[im][in][r] * scX[row] * yv;
      }
    }
  }
}

extern "C" void kernel_launch(void* const* d_in, const int* in_sizes, int n_in,
                              void* d_out, int out_size, void* d_ws,
                              size_t ws_size, hipStream_t stream) {
  const float* xs = (const float*)d_in[0];   // (8,4096,512) f32
  const float* spk = (const float*)d_in[1];  // (8,256,512) f32
  float* out = (float*)d_out;                // (8,4096,256) f32
  short* bp = (short*)d_ws;                  // 2 MB packed bf16 B (frag order)

  hipLaunchKernelGGL(cos_packB_kernel, dim3(512), dim3(256), 0, stream, spk,
                     bp);
  hipLaunchKernelGGL(cos_fused_kernel, dim3(512), dim3(256), 0, stream, xs,
                     bp, out);
}